// Round 4
// baseline (414.184 us; speedup 1.0000x reference)
//
#include <hip/hip_runtime.h>
#include <hip/hip_bf16.h>

#define HD 64
#define ED 16
#define NU 100000
#define NI 200000
#define NN 300000
#define NE 1250000
#define NP 14

#define RB 512                         // rows per bucket (9 bits)
#define NBKT ((NN + RB - 1) / RB)      // 586 buckets
#define NR8 (NBKT * RB)                // 300032 perm slots (tail = -1)
#define A_ITEMS 16
#define A_CHUNK (256 * A_ITEMS)        // 4096 edges per binning block
#define A_BLOCKS ((NE + A_CHUNK - 1) / A_CHUNK)   // 306
#define DBINS 64                       // degree-sort bins (deg clamped at 63)

typedef __hip_bfloat16 bf16;
typedef unsigned short ushort8v __attribute__((ext_vector_type(8)));

__device__ __forceinline__ float bf2f(unsigned short u) {
    union { unsigned int i; float f; } c; c.i = ((unsigned int)u) << 16; return c.f;
}
__device__ __forceinline__ unsigned short f2b(float x) {
    bf16 h = __float2bfloat16(x);
    unsigned short u; __builtin_memcpy(&u, &h, 2); return u;
}

// ---------------------------------------------------------------------------
// LayerNorm of input embeddings, 8-lane group per row (lane = 8 dims).
// Also converts eigs -> bf16 eb (2 elems/lane, packed 4-B store).
// ---------------------------------------------------------------------------
__global__ void ln_kernel(const float* __restrict__ user_emb,
                          const float* __restrict__ item_emb,
                          const float* __restrict__ eigs,
                          bf16* __restrict__ yb,
                          bf16* __restrict__ eb)
{
    const int tid = blockIdx.x * blockDim.x + threadIdx.x;
    const int r   = tid >> 3;
    const int sub = tid & 7;
    if (r >= NN) return;
    const float* src = (r < NU) ? user_emb + (size_t)r * HD
                                : item_emb + (size_t)(r - NU) * HD;
    const float4 lo = *reinterpret_cast<const float4*>(src + sub * 8);
    const float4 hi = *reinterpret_cast<const float4*>(src + sub * 8 + 4);
    float x[8] = {lo.x, lo.y, lo.z, lo.w, hi.x, hi.y, hi.z, hi.w};

    float sm = 0.0f, sq = 0.0f;
#pragma unroll
    for (int j = 0; j < 8; ++j) { sm += x[j]; sq += x[j] * x[j]; }
    sm += __shfl_xor(sm, 1, 64); sq += __shfl_xor(sq, 1, 64);
    sm += __shfl_xor(sm, 2, 64); sq += __shfl_xor(sq, 2, 64);
    sm += __shfl_xor(sm, 4, 64); sq += __shfl_xor(sq, 4, 64);
    const float mu  = sm * (1.0f / 64.0f);
    const float var = sq * (1.0f / 64.0f) - mu * mu;
    const float inv = rsqrtf(var + 1e-5f);

    ushort8v w;
#pragma unroll
    for (int j = 0; j < 8; ++j) w[j] = f2b((x[j] - mu) * inv);
    *reinterpret_cast<ushort8v*>(yb + (size_t)r * HD + sub * 8) = w;

    // bf16 eig table: 2 elems/lane, one packed 4-B store
    const float2 ev = *reinterpret_cast<const float2*>(eigs + (size_t)r * ED + sub * 2);
    const unsigned int packed = (unsigned int)f2b(ev.x) | ((unsigned int)f2b(ev.y) << 16);
    *reinterpret_cast<unsigned int*>(eb + (size_t)r * ED + sub * 2) = packed;
}

// ------------------- CSR build, stage A1: bucket histogram ------------------
__global__ void bkt_count_kernel(const int* __restrict__ row,
                                 int* __restrict__ bkt_cnt)
{
    __shared__ int hist[NBKT];
    const int tid = threadIdx.x;
    for (int j = tid; j < NBKT; j += 256) hist[j] = 0;
    __syncthreads();
    const int base = blockIdx.x * A_CHUNK;
#pragma unroll
    for (int i = 0; i < A_ITEMS; ++i) {
        const int idx = base + i * 256 + tid;
        if (idx < NE) atomicAdd(&hist[row[idx] >> 9], 1);
    }
    __syncthreads();
    for (int j = tid; j < NBKT; j += 256) {
        const int h = hist[j];
        if (h) atomicAdd(&bkt_cnt[j], h);
    }
}

// ------------- stage A2: exclusive scan of bucket counts (1 blk) -----------
__global__ void bkt_scan_kernel(const int* __restrict__ bkt_cnt,
                                int* __restrict__ bkt_base,
                                int* __restrict__ wq_bkt)
{
    __shared__ int s[1024];
    const int t = threadIdx.x;
    const int v = (t < NBKT) ? bkt_cnt[t] : 0;
    s[t] = v;
    __syncthreads();
    for (int off = 1; off < 1024; off <<= 1) {
        int x = (t >= off) ? s[t - off] : 0;
        __syncthreads();
        s[t] += x;
        __syncthreads();
    }
    if (t < NBKT) {
        const int excl = s[t] - v;
        bkt_base[t] = excl;
        wq_bkt[t]   = excl;
        if (t == NBKT - 1) bkt_base[NBKT] = s[t];   // == NE
    }
}

// --------- stage A3: bin edges into buckets (packed 4-B pairs) -------------
__global__ void bkt_scatter_kernel(const int* __restrict__ row,
                                   const int* __restrict__ col,
                                   const int* __restrict__ pt,
                                   int* __restrict__ wq_bkt,
                                   int* __restrict__ pairs)
{
    __shared__ int hist[NBKT];
    __shared__ int rbase[NBKT];
    __shared__ int roff[NBKT];
    const int tid = threadIdx.x;
    for (int j = tid; j < NBKT; j += 256) { hist[j] = 0; roff[j] = 0; }
    __syncthreads();

    const int base = blockIdx.x * A_CHUNK;
#pragma unroll
    for (int i = 0; i < A_ITEMS; ++i) {
        const int idx = base + i * 256 + tid;
        if (idx < NE) atomicAdd(&hist[row[idx] >> 9], 1);
    }
    __syncthreads();
    for (int j = tid; j < NBKT; j += 256) {
        const int h = hist[j];
        if (h) rbase[j] = atomicAdd(&wq_bkt[j], h);
    }
    __syncthreads();
#pragma unroll
    for (int i = 0; i < A_ITEMS; ++i) {
        const int idx = base + i * 256 + tid;
        if (idx < NE) {
            const int r = row[idx];
            const int b = r >> 9;
            const int v = col[idx] | (pt[idx] << 19) | ((r & (RB - 1)) << 23);
            const int o = atomicAdd(&roff[b], 1);
            pairs[rbase[b] + o] = v;
        }
    }
}

// --------- stage B: per-bucket sort by row + eig-dot precompute ------------
// One block per bucket. Also emits a within-bucket degree-sorted row
// permutation (rowperm) so each 8-row attention wave carries near-equal
// degree -> removes the max-of-8 Poisson divergence waste (~2x on the
// edge loop). Invalid tail slots get -1.
__global__ void bkt_sort_kernel(const int* __restrict__ bkt_base,
                                const int* __restrict__ pairs,
                                const float* __restrict__ eigs,
                                const bf16* __restrict__ eb,
                                int* __restrict__ rowptr,
                                int* __restrict__ cnt,
                                int2* __restrict__ epacked,
                                int* __restrict__ rowperm)
{
    __shared__ int rcnt[RB], lrp[RB], wq2[RB], ssum[256];
    __shared__ int dhist[DBINS], dbase[DBINS];
    __shared__ float estage[RB * ED];
    const int tid = threadIdx.x;
    const int b   = blockIdx.x;
    const int r0  = b * RB;
    const int s   = bkt_base[b];
    const int e   = bkt_base[b + 1];

    for (int j = tid; j < RB; j += 256) { rcnt[j] = 0; wq2[j] = 0; rowperm[r0 + j] = -1; }
    for (int j = tid; j < DBINS; j += 256) dhist[j] = 0;
    for (int k = tid; k < RB * ED; k += 256) {
        const int g = r0 * ED + k;
        estage[k] = (g < NN * ED) ? eigs[g] : 0.0f;
    }
    __syncthreads();

    for (int i = s + tid; i < e; i += 256)
        atomicAdd(&rcnt[(pairs[i] >> 23) & (RB - 1)], 1);
    __syncthreads();

    const int a0 = rcnt[2 * tid], a1 = rcnt[2 * tid + 1];
    ssum[tid] = a0 + a1;
    __syncthreads();
    for (int off = 1; off < 256; off <<= 1) {
        int x = (tid >= off) ? ssum[tid - off] : 0;
        __syncthreads();
        ssum[tid] += x;
        __syncthreads();
    }
    const int excl = ssum[tid] - (a0 + a1);
    lrp[2 * tid]     = excl;
    lrp[2 * tid + 1] = excl + a0;
    {
        const int r = r0 + 2 * tid;
        if (r < NN)     { rowptr[r]     = s + excl;      cnt[r]     = a0; }
        if (r + 1 < NN) { rowptr[r + 1] = s + excl + a0; cnt[r + 1] = a1; }
    }
    __syncthreads();

    // ---- within-bucket counting sort by degree -> rowperm ----
    const int ra   = r0 + 2 * tid;
    const int bin0 = (a0 < DBINS - 1) ? a0 : (DBINS - 1);
    const int bin1 = (a1 < DBINS - 1) ? a1 : (DBINS - 1);
    if (ra < NN)     atomicAdd(&dhist[bin0], 1);
    if (ra + 1 < NN) atomicAdd(&dhist[bin1], 1);
    __syncthreads();
    ssum[tid] = (tid < DBINS) ? dhist[tid] : 0;
    __syncthreads();
    for (int off = 1; off < DBINS; off <<= 1) {
        int x = (tid >= off) ? ssum[tid - off] : 0;
        __syncthreads();
        ssum[tid] += x;
        __syncthreads();
    }
    if (tid < DBINS) { dbase[tid] = ssum[tid] - dhist[tid]; dhist[tid] = 0; }
    __syncthreads();
    if (ra < NN)     rowperm[r0 + dbase[bin0] + atomicAdd(&dhist[bin0], 1)] = ra;
    if (ra + 1 < NN) rowperm[r0 + dbase[bin1] + atomicAdd(&dhist[bin1], 1)] = ra + 1;
    __syncthreads();   // defensive: separate perm phase from epacked scatter

    for (int i = s + tid; i < e; i += 256) {
        const int v  = pairs[i];
        const int rl = (v >> 23) & (RB - 1);
        const int c  = v & 0x7FFFF;
        const ushort8v* ep = reinterpret_cast<const ushort8v*>(eb + (size_t)c * ED);
        const ushort8v q0 = ep[0], q1 = ep[1];
        const float* er = estage + rl * ED;
        float d = 0.0f;
#pragma unroll
        for (int j = 0; j < 8; ++j) d += bf2f(q0[j]) * er[j];
#pragma unroll
        for (int j = 0; j < 8; ++j) d += bf2f(q1[j]) * er[j + 8];
        const int o   = atomicAdd(&wq2[rl], 1);
        const int pos = s + lrp[rl] + o;
        epacked[pos] = make_int2(v & 0x7FFFFF, __float_as_int(d));
    }
}

// ---------------------------------------------------------------------------
// Fused attention, single sweep, 8-lane group per row (exclusive owner).
// Rows walked through rowperm (degree-sorted within bucket) so the 8 rows
// of a wave have near-equal degree. Edge loop is batched by 8: broadcast
// the whole epacked batch, issue ALL yb gathers up front (8x memory-level
// parallelism vs load-then-consume), then consume; next epacked batch is
// prefetched under the current batch's compute.
//   out = 0.5*(sum e0*y[c])/d0 + 0.5*(sum e1*y[c])/d1
// LAYER 0 epilogue: in-register LayerNorm(out1) -> yb_next; io=(emb0+out1)/3.
// LAYER 1 epilogue: io += out2/3 -> final mean in d_out.
// ---------------------------------------------------------------------------
template <int LAYER>
__global__ void attn_row_kernel(const bf16* __restrict__ yb,
                                const int* __restrict__ rowptr,
                                const int* __restrict__ cnt,
                                const int2* __restrict__ epacked,
                                const int* __restrict__ rowperm,
                                const float* __restrict__ lambda0,
                                const float* __restrict__ pemb,
                                const float* __restrict__ user_emb,
                                const float* __restrict__ item_emb,
                                bf16* __restrict__ yb_next,
                                float* __restrict__ io)
{
    __shared__ float e1tab[NP];
    if (threadIdx.x < NP)
        e1tab[threadIdx.x] = __expf(pemb[LAYER * NP + threadIdx.x]);
    __syncthreads();

    const int tid  = blockIdx.x * blockDim.x + threadIdx.x;
    const int g    = tid >> 3;
    const int sub  = tid & 7;
    const int lane = (int)(threadIdx.x & 63);
    const int r    = rowperm[g];
    if (r < 0) return;                    // tail slots (32 of 300032)
    const int deg = cnt[r];
    if (LAYER == 1 && deg == 0) return;   // out2 row = 0: io unchanged

    const int start = rowptr[r];
    const float lam = __expf(lambda0[LAYER]);

    float yrf[8];
    {
        ushort8v u = *reinterpret_cast<const ushort8v*>(yb + (size_t)r * HD + sub * 8);
#pragma unroll
        for (int j = 0; j < 8; ++j) yrf[j] = bf2f(u[j]);
    }

    float U0[8], U1[8];
#pragma unroll
    for (int j = 0; j < 8; ++j) { U0[j] = 0.0f; U1[j] = 0.0f; }
    float d0 = 0.0f, d1 = 0.0f;

    // deg is uniform across the 8-lane group, so all lanes of a group take
    // identical trip counts and every shfl below stays within the group.
    int2 myv = (sub < deg) ? epacked[start + sub] : make_int2(0, 0);
    for (int k0 = 0; k0 < deg; k0 += 8) {
        // prefetch next epacked batch under this batch's compute
        const bool more = (k0 + 8) < deg;
        int2 nxt = make_int2(0, 0);
        if (more && (k0 + 8 + sub) < deg) nxt = epacked[start + k0 + 8 + sub];

        // broadcast the batch's (v, edot) to all lanes of the group
        int   vv[8];
        float ee[8];
#pragma unroll
        for (int kk = 0; kk < 8; ++kk) {
            const int src = (lane & ~7) + kk;
            vv[kk] = __shfl(myv.x, src, 64);
            ee[kk] = __int_as_float(__shfl(myv.y, src, 64));
        }

        const int nb = ((deg - k0) < 8) ? (deg - k0) : 8;

        // issue all gathers up front: nb cache lines in flight per group
        ushort8v uc[8];
#pragma unroll
        for (int kk = 0; kk < 8; ++kk) {
            if (kk < nb)
                uc[kk] = *reinterpret_cast<const ushort8v*>(
                    yb + (size_t)(vv[kk] & 0x7FFFF) * HD + sub * 8);
        }

        // consume
#pragma unroll
        for (int kk = 0; kk < 8; ++kk) {
            if (kk < nb) {
                float yc[8];
                float sdot = 0.0f;
#pragma unroll
                for (int j = 0; j < 8; ++j) { yc[j] = bf2f(uc[kk][j]); sdot += yrf[j] * yc[j]; }
                sdot += __shfl_xor(sdot, 1, 64);
                sdot += __shfl_xor(sdot, 2, 64);
                sdot += __shfl_xor(sdot, 4, 64);

                const float e0 = __expf(sdot * 0.125f + lam * ee[kk]);
                const float e1 = e1tab[(vv[kk] >> 19) & 15];
                d0 += e0; d1 += e1;
#pragma unroll
                for (int j = 0; j < 8; ++j) {
                    U0[j] += e0 * yc[j];
                    U1[j] += e1 * yc[j];
                }
            }
        }
        myv = nxt;
    }

    const float i0 = deg ? 0.5f / d0 : 0.0f;
    const float i1 = deg ? 0.5f / d1 : 0.0f;
    float acc[8];
#pragma unroll
    for (int j = 0; j < 8; ++j) acc[j] = i0 * U0[j] + i1 * U1[j];

    float* iorow = io + (size_t)r * HD + sub * 8;
    if (LAYER == 0) {
        float sm = 0.0f, sq = 0.0f;
#pragma unroll
        for (int j = 0; j < 8; ++j) { sm += acc[j]; sq += acc[j] * acc[j]; }
        sm += __shfl_xor(sm, 1, 64); sq += __shfl_xor(sq, 1, 64);
        sm += __shfl_xor(sm, 2, 64); sq += __shfl_xor(sq, 2, 64);
        sm += __shfl_xor(sm, 4, 64); sq += __shfl_xor(sq, 4, 64);
        const float mu  = sm * (1.0f / 64.0f);
        const float var = sq * (1.0f / 64.0f) - mu * mu;
        const float inv = rsqrtf(var + 1e-5f);
        ushort8v w;
#pragma unroll
        for (int j = 0; j < 8; ++j) w[j] = f2b((acc[j] - mu) * inv);
        *reinterpret_cast<ushort8v*>(yb_next + (size_t)r * HD + sub * 8) = w;

        const float* e0p = (r < NU) ? user_emb + (size_t)r * HD + sub * 8
                                    : item_emb + (size_t)(r - NU) * HD + sub * 8;
        const float4 lo = *reinterpret_cast<const float4*>(e0p);
        const float4 hi = *reinterpret_cast<const float4*>(e0p + 4);
        const float third = 1.0f / 3.0f;
        *reinterpret_cast<float4*>(iorow) =
            make_float4((lo.x + acc[0]) * third, (lo.y + acc[1]) * third,
                        (lo.z + acc[2]) * third, (lo.w + acc[3]) * third);
        *reinterpret_cast<float4*>(iorow + 4) =
            make_float4((hi.x + acc[4]) * third, (hi.y + acc[5]) * third,
                        (hi.z + acc[6]) * third, (hi.w + acc[7]) * third);
    } else {
        const float third = 1.0f / 3.0f;
        float4 lo = *reinterpret_cast<const float4*>(iorow);
        float4 hi = *reinterpret_cast<const float4*>(iorow + 4);
        lo.x += acc[0] * third; lo.y += acc[1] * third;
        lo.z += acc[2] * third; lo.w += acc[3] * third;
        hi.x += acc[4] * third; hi.y += acc[5] * third;
        hi.z += acc[6] * third; hi.w += acc[7] * third;
        *reinterpret_cast<float4*>(iorow)     = lo;
        *reinterpret_cast<float4*>(iorow + 4) = hi;
    }
}

extern "C" void kernel_launch(void* const* d_in, const int* in_sizes, int n_in,
                              void* d_out, int out_size, void* d_ws, size_t ws_size,
                              hipStream_t stream)
{
    const float* user_emb = (const float*)d_in[0];
    const float* item_emb = (const float*)d_in[1];
    const float* eigs     = (const float*)d_in[2];
    const float* lambda0  = (const float*)d_in[3];
    const float* pemb     = (const float*)d_in[4];
    const int*   indices  = (const int*)d_in[5];
    const int*   ptype    = (const int*)d_in[6];
    const int*   row = indices;
    const int*   col = indices + NE;

    float* io = (float*)d_out;                        // NN*HD fp32 accumulator
    char*  ws = (char*)d_ws;
    bf16* yb       = (bf16*)ws;                       // 38.4 MB
    bf16* yb2      = yb + (size_t)NN * HD;            // 38.4 MB
    bf16* eb       = yb2 + (size_t)NN * HD;           //  9.6 MB
    int*  pairs    = (int*)(eb + (size_t)NN * ED);    // NE      (5 MB)
    int2* epacked  = (int2*)(pairs + NE);             // NE int2 (10 MB)
    int*  rowptr   = (int*)(epacked + NE);            // NN
    int*  cnt      = rowptr + NN;                     // NN
    int*  bkt_cnt  = cnt + NN;                        // NBKT
    int*  bkt_base = bkt_cnt + NBKT;                  // NBKT+1
    int*  wq_bkt   = bkt_base + NBKT + 1;             // NBKT
    int*  rowperm  = wq_bkt + NBKT;                   // NR8 (1.2 MB)
    // total ws ~ 105 MB

    const dim3 blk(256);
    const int grid8 = (NR8 * 8) / 256;                // 8-lane group per perm slot

    // ---- LayerNorm + bf16 eig table (eb consumed by bkt_sort) ----
    ln_kernel<<<(NN * 8 + 255) / 256, blk, 0, stream>>>(user_emb, item_emb, eigs, yb, eb);

    // ---- CSR build: two-level binned counting sort + degree perm ----
    hipMemsetAsync(bkt_cnt, 0, NBKT * sizeof(int), stream);
    bkt_count_kernel<<<A_BLOCKS, blk, 0, stream>>>(row, bkt_cnt);
    bkt_scan_kernel<<<1, 1024, 0, stream>>>(bkt_cnt, bkt_base, wq_bkt);
    bkt_scatter_kernel<<<A_BLOCKS, blk, 0, stream>>>(row, col, ptype, wq_bkt, pairs);
    bkt_sort_kernel<<<NBKT, blk, 0, stream>>>(bkt_base, pairs, eigs, eb,
                                              rowptr, cnt, epacked, rowperm);

    // ---- layer 0 (attn fuses ln2 + final-mean prep) ----
    attn_row_kernel<0><<<grid8, blk, 0, stream>>>(yb, rowptr, cnt, epacked, rowperm,
                                                  lambda0, pemb, user_emb,
                                                  item_emb, yb2, io);
    // ---- layer 1 (adds out2/3 -> final mean in d_out) ----
    attn_row_kernel<1><<<grid8, blk, 0, stream>>>(yb2, rowptr, cnt, epacked, rowperm,
                                                  lambda0, pemb, user_emb,
                                                  item_emb, nullptr, io);
}